// Round 1
// baseline (312.393 us; speedup 1.0000x reference)
//
#include <hip/hip_runtime.h>
#include <math.h>

// Problem constants
#define N_CELLS 65536
#define HIDW    256
#define INW     128
#define OUTW    128
#define N1      256   // fused layer-1 width (a-branch 0..127, g-branch 128..255)

// Workspace layout (float offsets). Total ~1.16 MB.
#define OFF_W1T   0                        // [256][256]  W1t[k][n] = W1[n][k+128]
#define OFF_W2T   (OFF_W1T  + 256*256)     // [256][128]  W2t[k][o] = k<128? Wa2[o][k] : -Wg2[o][k-128]
#define OFF_XW1B  (OFF_W2T  + 256*128)     // [256]       b1[n] + sum_j x[j]*W1[n][j]
#define OFF_B2D   (OFF_XW1B + 256)         // [128]       ba2 - bg2
#define OFF_PT    (OFF_B2D  + 128)         // [1024]      per-block sum(tension)
#define OFF_PE    (OFF_PT   + 1024)        // [1024]      per-block sum(exp(tension))
#define OFF_POUT  (OFF_PE   + 1024)        // [1024][128] per-block sum(e*out)
#define OFF_GBUF  (OFF_POUT + 1024*128)    // [64][129]   gathered out rows + tension
#define OFF_HID   (OFF_GBUF + 64*129)      // [64][256]   GRU hid for gathered cells
#define OFF_HIDN  (OFF_HID  + 64*256)      // [64][256]   after nat transform
#define OFF_PLIM  (OFF_HIDN + 64*256)      // [32][256]   per-m limit partial
#define OFF_PCOL  (OFF_PLIM + 32*256)      // [32][256]   per-m colimit partial
#define OFF_SINV  (OFF_PCOL + 32*256)      // [1]         1/sum(exp(t))

// ---------------------------------------------------------------------------
// Prep: build W1t, W2t, xw1b, b2d.  Grid 257 x 256.
// ---------------------------------------------------------------------------
__global__ __launch_bounds__(256) void k_prep(
    const float* __restrict__ x,
    const float* __restrict__ Wa1, const float* __restrict__ ba1,
    const float* __restrict__ Wa2, const float* __restrict__ ba2,
    const float* __restrict__ Wg1, const float* __restrict__ bg1,
    const float* __restrict__ Wg2, const float* __restrict__ bg2,
    float* __restrict__ ws)
{
    const int b = blockIdx.x, t = threadIdx.x;
    if (b < 256) {
        const int k = b, n = t;
        // W1t[k][n] = (n<128 ? Wa1 : Wg1)[n%128][128+k]   (hidden columns only)
        float v = (n < 128) ? Wa1[n * 384 + 128 + k] : Wg1[(n - 128) * 384 + 128 + k];
        ws[OFF_W1T + k * 256 + n] = v;
        if (t < 128) {
            const int o = t;
            float w2 = (k < 128) ? Wa2[o * 128 + k] : -Wg2[o * 128 + (k - 128)];
            ws[OFF_W2T + k * 128 + o] = w2;
        }
    } else {
        const int n = t;
        const float* wr = (n < 128) ? &Wa1[n * 384] : &Wg1[(n - 128) * 384];
        float s = (n < 128) ? ba1[n] : bg1[n - 128];
        for (int j = 0; j < 128; ++j) s = fmaf(x[j], wr[j], s);
        ws[OFF_XW1B + n] = s;
        if (n < 128) ws[OFF_B2D + n] = ba2[n] - bg2[n];
    }
}

// ---------------------------------------------------------------------------
// Main: per 64-cell tile -> h1 = relu(hiddens@W1t + xw1b) ; out = h1@W2t + b2d
// tension, e=exp(tension), block partials, and gathered rows for the GRU path.
// Grid 1024 x 512.  LDS ~99KB -> 1 block/CU, 8 waves.
// ---------------------------------------------------------------------------
__global__ __launch_bounds__(512) void k_main(
    const float* __restrict__ hiddens,
    const int* __restrict__ msrc, const int* __restrict__ mtgt,
    float* __restrict__ ws)
{
    __shared__ float h_lds[256 * 64];   // [k][cell] then reused as h1t[n][cell], then out_sm
    __shared__ float w_lds[32 * 256];   // weight K-chunk, reused for reductions
    __shared__ float e_lds[64];
    __shared__ float t_lds[64];

    const int tid = threadIdx.x;
    const int blk = blockIdx.x;
    const int cell0 = blk * 64;
    const float* W1t = ws + OFF_W1T;
    const float* W2t = ws + OFF_W2T;

    // ---- stage hiddens tile transposed: h_lds[k][c] = hiddens[cell0+c][k]
    {
        const int c = tid & 63, kq = tid >> 6;  // kq 0..7 covers 32 k each
        const float* src = hiddens + (size_t)(cell0 + c) * 256 + kq * 32;
#pragma unroll
        for (int j = 0; j < 8; ++j) {
            float4 v = *(const float4*)(src + j * 4);
            const int k = kq * 32 + j * 4;
            h_lds[(k + 0) * 64 + c] = v.x;
            h_lds[(k + 1) * 64 + c] = v.y;
            h_lds[(k + 2) * 64 + c] = v.z;
            h_lds[(k + 3) * 64 + c] = v.w;
        }
    }

    const int cellq = tid & 15;   // 4 cells each
    const int nq    = tid >> 4;   // 0..31 : 8 n's (GEMM1) / 4 o's (GEMM2)

    // ---- GEMM1: acc[c][n] = xw1b[n] + sum_k h[c][k] * W1t[k][n]
    float acc[4][8];
    {
        float4 xa = *(const float4*)(ws + OFF_XW1B + nq * 8);
        float4 xb = *(const float4*)(ws + OFF_XW1B + nq * 8 + 4);
#pragma unroll
        for (int jc = 0; jc < 4; ++jc) {
            acc[jc][0] = xa.x; acc[jc][1] = xa.y; acc[jc][2] = xa.z; acc[jc][3] = xa.w;
            acc[jc][4] = xb.x; acc[jc][5] = xb.y; acc[jc][6] = xb.z; acc[jc][7] = xb.w;
        }
    }
    for (int kc = 0; kc < 256; kc += 32) {
        __syncthreads();
        {   // stage W1t chunk [32][256]
            const int kk = tid >> 4, n0 = (tid & 15) * 16;
            const float4* s = (const float4*)(W1t + (kc + kk) * 256 + n0);
            float4* d = (float4*)(&w_lds[kk * 256 + n0]);
            d[0] = s[0]; d[1] = s[1]; d[2] = s[2]; d[3] = s[3];
        }
        __syncthreads();
#pragma unroll
        for (int k = 0; k < 32; ++k) {
            float4 a  = *(const float4*)(&h_lds[(kc + k) * 64 + cellq * 4]);
            float4 b0 = *(const float4*)(&w_lds[k * 256 + nq * 8]);
            float4 b1 = *(const float4*)(&w_lds[k * 256 + nq * 8 + 4]);
            const float av[4] = {a.x, a.y, a.z, a.w};
            const float bv[8] = {b0.x, b0.y, b0.z, b0.w, b1.x, b1.y, b1.z, b1.w};
#pragma unroll
            for (int jc = 0; jc < 4; ++jc)
#pragma unroll
                for (int jn = 0; jn < 8; ++jn)
                    acc[jc][jn] = fmaf(av[jc], bv[jn], acc[jc][jn]);
        }
    }
    __syncthreads();
    // ---- relu, write h1 transposed back into h_lds [n][c]
#pragma unroll
    for (int jn = 0; jn < 8; ++jn) {
        const int n = nq * 8 + jn;
#pragma unroll
        for (int jc = 0; jc < 4; ++jc) {
            const int c = cellq * 4 + jc;
            h_lds[n * 64 + c] = fmaxf(acc[jc][jn], 0.0f);
        }
    }

    // ---- GEMM2: out[c][o] = b2d[o] + sum_n h1[c][n] * W2t[n][o]
    float acc2[4][4];
#pragma unroll
    for (int jc = 0; jc < 4; ++jc)
#pragma unroll
        for (int jo = 0; jo < 4; ++jo) acc2[jc][jo] = 0.0f;

    const int oq = nq;  // 0..31, 4 o's each
    for (int kc = 0; kc < 256; kc += 32) {
        __syncthreads();
        {   // stage W2t chunk [32][128]
            const int kk = tid >> 4, o0 = (tid & 15) * 8;
            const float4* s = (const float4*)(W2t + (kc + kk) * 128 + o0);
            float4* d = (float4*)(&w_lds[kk * 128 + o0]);
            d[0] = s[0]; d[1] = s[1];
        }
        __syncthreads();
#pragma unroll
        for (int k = 0; k < 32; ++k) {
            float4 a = *(const float4*)(&h_lds[(kc + k) * 64 + cellq * 4]);
            float4 b = *(const float4*)(&w_lds[k * 128 + oq * 4]);
            const float av[4] = {a.x, a.y, a.z, a.w};
            const float bv[4] = {b.x, b.y, b.z, b.w};
#pragma unroll
            for (int jc = 0; jc < 4; ++jc)
#pragma unroll
                for (int jo = 0; jo < 4; ++jo)
                    acc2[jc][jo] = fmaf(av[jc], bv[jo], acc2[jc][jo]);
        }
    }

    float outv[4][4];
    {
        float4 bb = *(const float4*)(ws + OFF_B2D + oq * 4);
        const float bv[4] = {bb.x, bb.y, bb.z, bb.w};
#pragma unroll
        for (int jc = 0; jc < 4; ++jc)
#pragma unroll
            for (int jo = 0; jo < 4; ++jo)
                outv[jc][jo] = acc2[jc][jo] + bv[jo];
    }

    // ---- out tile to LDS (stride 132, reuse h_lds region) for gathered rows
    __syncthreads();
#pragma unroll
    for (int jc = 0; jc < 4; ++jc) {
        const int c = cellq * 4 + jc;
        *(float4*)(&h_lds[c * 132 + oq * 4]) =
            make_float4(outv[jc][0], outv[jc][1], outv[jc][2], outv[jc][3]);
    }

    // ---- tension: partials in w_lds as [64 cells][32 oq]
#pragma unroll
    for (int jc = 0; jc < 4; ++jc) {
        float s = outv[jc][0] * outv[jc][0] + outv[jc][1] * outv[jc][1] +
                  outv[jc][2] * outv[jc][2] + outv[jc][3] * outv[jc][3];
        w_lds[(cellq * 4 + jc) * 32 + oq] = s;
    }
    __syncthreads();
    if (tid < 64) {
        float s = 0.0f;
#pragma unroll
        for (int q = 0; q < 32; ++q) s += w_lds[tid * 32 + q];
        const float tv = s * (1.0f / 128.0f);
        t_lds[tid] = tv;
        const float ev = expf(tv);
        e_lds[tid] = ev;
        float pt = tv, pe = ev;
        for (int off = 32; off > 0; off >>= 1) {
            pt += __shfl_down(pt, off);
            pe += __shfl_down(pe, off);
        }
        if (tid == 0) { ws[OFF_PT + blk] = pt; ws[OFF_PE + blk] = pe; }
    }
    __syncthreads();

    // ---- weighted out partial: sum_c e[c]*out[c][o]  -> w_lds as [128 o][16 cellq]
    {
        float w4[4];
#pragma unroll
        for (int jc = 0; jc < 4; ++jc) w4[jc] = e_lds[cellq * 4 + jc];
#pragma unroll
        for (int jo = 0; jo < 4; ++jo) {
            float s = w4[0] * outv[0][jo] + w4[1] * outv[1][jo] +
                      w4[2] * outv[2][jo] + w4[3] * outv[3][jo];
            w_lds[(oq * 4 + jo) * 16 + cellq] = s;
        }
    }
    __syncthreads();
    if (tid < 128) {
        float s = 0.0f;
#pragma unroll
        for (int q = 0; q < 16; ++q) s += w_lds[tid * 16 + q];
        ws[OFF_POUT + blk * 128 + tid] = s;
    }
    // ---- gathered rows for GRU path
    if (tid < 64) {
        const int cell = (tid < 32) ? msrc[tid] : mtgt[tid - 32];
        if ((cell >> 6) == blk) {
            const int c = cell & 63;
            float* g = ws + OFF_GBUF + tid * 129;
            for (int o = 0; o < 128; ++o) g[o] = h_lds[c * 132 + o];
            g[128] = t_lds[c];
        }
    }
}

// ---------------------------------------------------------------------------
// GRU for the 64 gathered cells. Grid 64 x 256 (thread t = hidden index).
// ---------------------------------------------------------------------------
__global__ __launch_bounds__(256) void k_gru(
    const float* __restrict__ hiddens,
    const float* __restrict__ W_ih, const float* __restrict__ W_hh,
    const float* __restrict__ b_ih, const float* __restrict__ b_hh,
    const int* __restrict__ msrc, const int* __restrict__ mtgt,
    float* __restrict__ ws)
{
    __shared__ float mi[129];
    __shared__ float hc[256];
    const int g = blockIdx.x, t = threadIdx.x;
    const int cell = (g < 32) ? msrc[g] : mtgt[g - 32];
    if (t < 129) mi[t] = ws[OFF_GBUF + g * 129 + t];
    hc[t] = hiddens[(size_t)cell * 256 + t];
    __syncthreads();

    float gi[3], gh[3];
#pragma unroll
    for (int p = 0; p < 3; ++p) {
        const int row = p * 256 + t;
        const float* wi = W_ih + row * 129;
        float s = b_ih[row];
        for (int j = 0; j < 129; ++j) s = fmaf(mi[j], wi[j], s);
        gi[p] = s;
        const float* wh = W_hh + row * 256;
        float s2 = b_hh[row];
        for (int j = 0; j < 256; ++j) s2 = fmaf(hc[j], wh[j], s2);
        gh[p] = s2;
    }
    const float r  = 1.0f / (1.0f + expf(-(gi[0] + gh[0])));
    const float z  = 1.0f / (1.0f + expf(-(gi[1] + gh[1])));
    const float nn = tanhf(gi[2] + r * gh[2]);
    ws[OFF_HID + g * 256 + t] = (1.0f - z) * nn + z * hc[t];
}

// ---------------------------------------------------------------------------
// Natural transformation (hid @ nat_w.T) when step%3==0, else copy. 64 x 256.
// ---------------------------------------------------------------------------
__global__ __launch_bounds__(256) void k_nat(
    const float* __restrict__ nat_w, const int* __restrict__ step,
    float* __restrict__ ws)
{
    __shared__ float hr[256];
    const int g = blockIdx.x, t = threadIdx.x;
    hr[t] = ws[OFF_HID + g * 256 + t];
    __syncthreads();
    float outv;
    if (step[0] % 3 == 0) {
        const float* wr = nat_w + t * 256;
        float s = 0.0f;
        for (int j = 0; j < 256; ++j) s = fmaf(hr[j], wr[j], s);
        outv = s;
    } else {
        outv = hr[t];
    }
    ws[OFF_HIDN + g * 256 + t] = outv;
}

// ---------------------------------------------------------------------------
// Morphism partials: limit/colimit contribution of morphism m. 32 x 256.
// ---------------------------------------------------------------------------
__global__ __launch_bounds__(256) void k_morph(
    const float* __restrict__ morph_w, float* __restrict__ ws)
{
    __shared__ float hs[256], ht[256];
    const int m = blockIdx.x, t = threadIdx.x;
    hs[t] = ws[OFF_HIDN + m * 256 + t];         // hid[morph_src[m]]
    ht[t] = ws[OFF_HIDN + (32 + m) * 256 + t];  // hid[morph_tgt[m]]
    __syncthreads();
    const float* wm = morph_w + (size_t)m * 65536;
    float L = 0.0f, C = 0.0f;
    for (int j = 0; j < 256; ++j) L = fmaf(wm[t * 256 + j], hs[j], L);
    for (int j = 0; j < 256; ++j) C = fmaf(wm[j * 256 + t], ht[j], C);
    ws[OFF_PLIM + m * 256 + t] = L;
    ws[OFF_PCOL + m * 256 + t] = C;
}

// ---------------------------------------------------------------------------
// Finalize scalars: cat_tension, avg_tension (-> d_out[128]), 1/S.  1 x 256.
// ---------------------------------------------------------------------------
__global__ __launch_bounds__(256) void k_final(float* __restrict__ ws,
                                               float* __restrict__ out)
{
    __shared__ float red[256];
    const int t = threadIdx.x;
    float L = 0.0f, C = 0.0f;
    for (int m = 0; m < 32; ++m) {
        L += ws[OFF_PLIM + m * 256 + t];
        C += ws[OFF_PCOL + m * 256 + t];
    }
    const float d = (L - C) * (1.0f / 32.0f);

    float pt = 0.0f, pe = 0.0f;
    for (int b = t; b < 1024; b += 256) { pt += ws[OFF_PT + b]; pe += ws[OFF_PE + b]; }

    red[t] = d * d; __syncthreads();
    for (int s = 128; s > 0; s >>= 1) { if (t < s) red[t] += red[t + s]; __syncthreads(); }
    const float cat = red[0] * (1.0f / 256.0f);
    __syncthreads();
    red[t] = pt; __syncthreads();
    for (int s = 128; s > 0; s >>= 1) { if (t < s) red[t] += red[t + s]; __syncthreads(); }
    const float tsum = red[0];
    __syncthreads();
    red[t] = pe; __syncthreads();
    for (int s = 128; s > 0; s >>= 1) { if (t < s) red[t] += red[t + s]; __syncthreads(); }
    if (t == 0) {
        out[128] = tsum * (1.0f / 65536.0f) + 0.1f * cat;
        ws[OFF_SINV] = 1.0f / red[0];
    }
}

// ---------------------------------------------------------------------------
// combined_out[o] = (1/S) * sum_b pout[b][o].  128 x 256.
// ---------------------------------------------------------------------------
__global__ __launch_bounds__(256) void k_out(const float* __restrict__ ws,
                                             float* __restrict__ out)
{
    __shared__ float red[256];
    const int o = blockIdx.x, t = threadIdx.x;
    float s = 0.0f;
    for (int b = t; b < 1024; b += 256) s += ws[OFF_POUT + b * 128 + o];
    red[t] = s; __syncthreads();
    for (int k = 128; k > 0; k >>= 1) { if (t < k) red[t] += red[t + k]; __syncthreads(); }
    if (t == 0) out[o] = red[0] * ws[OFF_SINV];
}

// ---------------------------------------------------------------------------
extern "C" void kernel_launch(void* const* d_in, const int* in_sizes, int n_in,
                              void* d_out, int out_size, void* d_ws, size_t ws_size,
                              hipStream_t stream)
{
    const float* x     = (const float*)d_in[0];
    const float* hidd  = (const float*)d_in[1];
    const float* Wa1   = (const float*)d_in[2];
    const float* ba1   = (const float*)d_in[3];
    const float* Wa2   = (const float*)d_in[4];
    const float* ba2   = (const float*)d_in[5];
    const float* Wg1   = (const float*)d_in[6];
    const float* bg1   = (const float*)d_in[7];
    const float* Wg2   = (const float*)d_in[8];
    const float* bg2   = (const float*)d_in[9];
    const float* W_ih  = (const float*)d_in[10];
    const float* W_hh  = (const float*)d_in[11];
    const float* b_ih  = (const float*)d_in[12];
    const float* b_hh  = (const float*)d_in[13];
    const float* nat_w = (const float*)d_in[14];
    const float* mw    = (const float*)d_in[15];
    const int*   msrc  = (const int*)d_in[16];
    const int*   mtgt  = (const int*)d_in[17];
    const int*   step  = (const int*)d_in[18];

    float* out = (float*)d_out;
    float* ws  = (float*)d_ws;   // needs ~1.16 MB

    k_prep <<<257, 256, 0, stream>>>(x, Wa1, ba1, Wa2, ba2, Wg1, bg1, Wg2, bg2, ws);
    k_main <<<1024, 512, 0, stream>>>(hidd, msrc, mtgt, ws);
    k_gru  <<<64, 256, 0, stream>>>(hidd, W_ih, W_hh, b_ih, b_hh, msrc, mtgt, ws);
    k_nat  <<<64, 256, 0, stream>>>(nat_w, step, ws);
    k_morph<<<32, 256, 0, stream>>>(mw, ws);
    k_final<<<1, 256, 0, stream>>>(ws, out);
    k_out  <<<128, 256, 0, stream>>>(ws, out);
}

// Round 2
// 200.219 us; speedup vs baseline: 1.5603x; 1.5603x over previous
//
#include <hip/hip_runtime.h>
#include <math.h>

#define N_CELLS 65536

// ---- workspace layout (float offsets) ----
#define OFF_W1B   0          // bf16 [8s][4kc][256n][8j] = 65536 u16 = 32768 f
#define OFF_W2A   32768      // bf16 [8s][4kc][128o][8j] = 32768 u16 = 16384 f
#define OFF_XW1B  49152      // f32 [256]
#define OFF_B2D   49408      // f32 [128]
#define OFF_PT    49536      // f32 [1024]
#define OFF_PE    50560      // f32 [1024]
#define OFF_POUT  51584      // f32 [1024][128]
#define OFF_GBUF  182656     // f32 [64][129]
#define OFF_PLIM  190912     // f32 [32][256]
#define OFF_PCOL  199104     // f32 [32][256]

typedef short bf16x8 __attribute__((ext_vector_type(8)));
typedef float f32x4  __attribute__((ext_vector_type(4)));

__device__ __forceinline__ unsigned short f2bf(float f) {
    unsigned u = __builtin_bit_cast(unsigned, f);
    u += 0x7FFFu + ((u >> 16) & 1u);          // round-to-nearest-even
    return (unsigned short)(u >> 16);
}

// ---------------------------------------------------------------------------
// Prep: pack W1 (hidden cols) and W2' into bf16 MFMA fragment layout,
// fold x@W1^T + b1 into xw1b, b2d = ba2-bg2.   Grid 257 x 256.
// ---------------------------------------------------------------------------
__global__ __launch_bounds__(256) void k_prep(
    const float* __restrict__ x,
    const float* __restrict__ Wa1, const float* __restrict__ ba1,
    const float* __restrict__ Wa2, const float* __restrict__ ba2,
    const float* __restrict__ Wg1, const float* __restrict__ bg1,
    const float* __restrict__ Wg2, const float* __restrict__ bg2,
    float* __restrict__ ws)
{
    const int b = blockIdx.x, t = threadIdx.x;
    unsigned short* w1b = (unsigned short*)(ws + OFF_W1B);
    unsigned short* w2a = (unsigned short*)(ws + OFF_W2A);
    if (b < 256) {
        const int n = b;           // t = k index 0..255 (bits: s=t>>5, kc=(t>>3)&3, j=t&7)
        const float* row = (n < 128) ? &Wa1[n * 384] : &Wg1[(n - 128) * 384];
        const int sk = ((t >> 5) * 4 + ((t >> 3) & 3));
        w1b[(sk * 256 + n) * 8 + (t & 7)] = f2bf(row[128 + t]);
        if (n < 128) {   // W2'[o=n][k=t] : k<128 -> Wa2, else -Wg2
            float w2 = (t < 128) ? Wa2[n * 128 + t] : -Wg2[n * 128 + (t - 128)];
            w2a[(sk * 128 + n) * 8 + (t & 7)] = f2bf(w2);
        }
    } else {
        const int n = t;
        const float* wr = (n < 128) ? &Wa1[n * 384] : &Wg1[(n - 128) * 384];
        float s = (n < 128) ? ba1[n] : bg1[n - 128];
        for (int j = 0; j < 128; ++j) s = fmaf(x[j], wr[j], s);
        ws[OFF_XW1B + n] = s;
        if (n < 128) ws[OFF_B2D + n] = ba2[n] - bg2[n];
    }
}

// ---------------------------------------------------------------------------
// Main: 64-cell tile, both GEMMs via mfma_f32_16x16x32_bf16 (swapped operands:
// D[n][cell]).  Grid 1024 x 512.  LDS = 80KB -> 2 blocks/CU.
// smem: [0,32K) hA  [32K,64K) h1A  [64K,80K) wbuf ; epilogue aliases:
//       out_sm f32[64][130] @0 ; part[4][64]/e/t @64K
// ---------------------------------------------------------------------------
__global__ __launch_bounds__(512, 4) void k_main(
    const float* __restrict__ hiddens,
    const int* __restrict__ msrc, const int* __restrict__ mtgt,
    float* __restrict__ ws)
{
    __shared__ __align__(16) char smem[81920];
    short* hA  = (short*)&smem[0];
    short* h1A = (short*)&smem[32768];
    short* wbf = (short*)&smem[65536];

    const int tid  = threadIdx.x;
    const int lane = tid & 63;
    const int wid  = tid >> 6;
    const int wn   = wid >> 1;          // 0..3 : n-group (64n) / o-group (32o)
    const int wc   = wid & 1;           // 0..1 : cell-group (32 cells)
    const int l15  = lane & 15;
    const int l4   = lane >> 4;         // 0..3
    const int blk  = blockIdx.x;
    const int cell0 = blk * 64;

    // ---- stage hiddens tile f32 -> bf16, fragment layout [kc][slot][8] ----
    for (int it = 0; it < 4; ++it) {
        const int idx = it * 512 + tid;       // 0..2047
        const int c = idx >> 5, q = idx & 31; // cell, kc
        const float4* src = (const float4*)(hiddens + (size_t)(cell0 + c) * 256 + q * 8);
        float4 va = src[0], vb = src[1];
        bf16x8 bv;
        bv[0] = (short)f2bf(va.x); bv[1] = (short)f2bf(va.y);
        bv[2] = (short)f2bf(va.z); bv[3] = (short)f2bf(va.w);
        bv[4] = (short)f2bf(vb.x); bv[5] = (short)f2bf(vb.y);
        bv[6] = (short)f2bf(vb.z); bv[7] = (short)f2bf(vb.w);
        const int slot = (c & 48) | ((c ^ q) & 15);
        *(bf16x8*)&hA[(q * 64 + slot) * 8] = bv;
    }

    // ---- GEMM1: D1[n][c] = sum_k W1[n][k] * h[c][k] ----
    const uint4* w1g = (const uint4*)(ws + OFF_W1B);
    const uint4* w2g = (const uint4*)(ws + OFF_W2A);
    f32x4 acc[4][2];
#pragma unroll
    for (int nt = 0; nt < 4; ++nt)
#pragma unroll
        for (int ct = 0; ct < 2; ++ct) acc[nt][ct] = (f32x4)0.f;

    uint4 wr0 = w1g[tid], wr1 = w1g[512 + tid];
    for (int s = 0; s < 8; ++s) {
        __syncthreads();
        ((uint4*)wbf)[tid] = wr0; ((uint4*)wbf)[512 + tid] = wr1;
        __syncthreads();
        if (s < 7) { wr0 = w1g[(s + 1) * 1024 + tid]; wr1 = w1g[(s + 1) * 1024 + 512 + tid]; }
        else       { wr0 = w2g[tid]; }   // prefetch GEMM2 chunk 0
        const int kcg = s * 4 + l4;
        bf16x8 afr[4], bfr[2];
#pragma unroll
        for (int nt = 0; nt < 4; ++nt)
            afr[nt] = *(const bf16x8*)&wbf[(l4 * 256 + wn * 64 + nt * 16 + l15) * 8];
#pragma unroll
        for (int ct = 0; ct < 2; ++ct) {
            const int slot = (wc * 32 + ct * 16) | ((l15 ^ kcg) & 15);
            bfr[ct] = *(const bf16x8*)&hA[(kcg * 64 + slot) * 8];
        }
#pragma unroll
        for (int nt = 0; nt < 4; ++nt)
#pragma unroll
            for (int ct = 0; ct < 2; ++ct)
                acc[nt][ct] = __builtin_amdgcn_mfma_f32_16x16x32_bf16(afr[nt], bfr[ct], acc[nt][ct], 0, 0, 0);
    }

    // ---- bias + relu + write h1 (bf16, fragment layout, k2 = n) ----
#pragma unroll
    for (int nt = 0; nt < 4; ++nt) {
#pragma unroll
        for (int r = 0; r < 4; ++r) {
            const int n = wn * 64 + nt * 16 + l4 * 4 + r;
            const float xb = ws[OFF_XW1B + n];
            const int kc2 = n >> 3, j2 = n & 7;
#pragma unroll
            for (int ct = 0; ct < 2; ++ct) {
                const int c = wc * 32 + ct * 16 + l15;
                float v = fmaxf(acc[nt][ct][r] + xb, 0.f);
                const int slot = (c & 48) | ((c ^ kc2) & 15);
                h1A[(kc2 * 64 + slot) * 8 + j2] = (short)f2bf(v);
            }
        }
    }

    // ---- GEMM2: D2[o][c] = sum_n W2'[o][n] * h1[c][n] ----
    f32x4 acc2[2][2];
#pragma unroll
    for (int ot = 0; ot < 2; ++ot)
#pragma unroll
        for (int ct = 0; ct < 2; ++ct) acc2[ot][ct] = (f32x4)0.f;

    for (int s = 0; s < 8; ++s) {
        __syncthreads();
        ((uint4*)wbf)[tid] = wr0;
        __syncthreads();
        if (s < 7) wr0 = w2g[(s + 1) * 512 + tid];
        const int kcg = s * 4 + l4;
        bf16x8 afr2[2], bfr2[2];
#pragma unroll
        for (int ot = 0; ot < 2; ++ot)
            afr2[ot] = *(const bf16x8*)&wbf[(l4 * 128 + wn * 32 + ot * 16 + l15) * 8];
#pragma unroll
        for (int ct = 0; ct < 2; ++ct) {
            const int slot = (wc * 32 + ct * 16) | ((l15 ^ kcg) & 15);
            bfr2[ct] = *(const bf16x8*)&h1A[(kcg * 64 + slot) * 8];
        }
#pragma unroll
        for (int ot = 0; ot < 2; ++ot)
#pragma unroll
            for (int ct = 0; ct < 2; ++ct)
                acc2[ot][ct] = __builtin_amdgcn_mfma_f32_16x16x32_bf16(afr2[ot], bfr2[ct], acc2[ot][ct], 0, 0, 0);
    }

    // ---- epilogue ----
    float outv[2][2][4];
#pragma unroll
    for (int ot = 0; ot < 2; ++ot)
#pragma unroll
        for (int r = 0; r < 4; ++r) {
            const int o = wn * 32 + ot * 16 + l4 * 4 + r;
            const float bd = ws[OFF_B2D + o];
#pragma unroll
            for (int ct = 0; ct < 2; ++ct)
                outv[ot][ct][r] = acc2[ot][ct][r] + bd;
        }
    __syncthreads();   // all LDS frag reads done; re-purpose smem

    float* out_sm = (float*)smem;                 // [64][130]
    float* part   = (float*)&smem[65536];         // [4][64]
    float* e_sm   = (float*)&smem[65536 + 1024];  // [64]
    float* t_sm   = (float*)&smem[65536 + 1280];  // [64]

#pragma unroll
    for (int ot = 0; ot < 2; ++ot)
#pragma unroll
        for (int ct = 0; ct < 2; ++ct) {
            const int c = wc * 32 + ct * 16 + l15;
#pragma unroll
            for (int r = 0; r < 4; ++r) {
                const int o = wn * 32 + ot * 16 + l4 * 4 + r;
                out_sm[c * 130 + o] = outv[ot][ct][r];
            }
        }
#pragma unroll
    for (int ct = 0; ct < 2; ++ct) {
        float sq = 0.f;
#pragma unroll
        for (int ot = 0; ot < 2; ++ot)
#pragma unroll
            for (int r = 0; r < 4; ++r) sq = fmaf(outv[ot][ct][r], outv[ot][ct][r], sq);
        sq += __shfl_xor(sq, 16);
        sq += __shfl_xor(sq, 32);
        if (l4 == 0) part[wn * 64 + wc * 32 + ct * 16 + l15] = sq;
    }
    __syncthreads();

    if (tid < 64) {
        const float tv = (part[tid] + part[64 + tid] + part[128 + tid] + part[192 + tid]) * (1.f / 128.f);
        const float ev = expf(tv);
        t_sm[tid] = tv; e_sm[tid] = ev;
        float pt = tv, pe = ev;
        for (int off = 32; off > 0; off >>= 1) {
            pt += __shfl_down(pt, off);
            pe += __shfl_down(pe, off);
        }
        if (tid == 0) { ws[OFF_PT + blk] = pt; ws[OFF_PE + blk] = pe; }
    }
    __syncthreads();

    if (tid < 128) {
        float s = 0.f;
        for (int c = 0; c < 64; ++c) s = fmaf(e_sm[c], out_sm[c * 130 + tid], s);
        ws[OFF_POUT + blk * 128 + tid] = s;
    } else if (tid < 192) {
        const int g = tid - 128;
        const int cell = (g < 32) ? msrc[g] : mtgt[g - 32];
        if ((cell >> 6) == blk) {
            const int c = cell & 63;
            float* gb = ws + OFF_GBUF + g * 129;
            for (int o = 0; o < 128; ++o) gb[o] = out_sm[c * 130 + o];
            gb[128] = t_sm[c];
        }
    }
}

// ---------------------------------------------------------------------------
// Tail: GRU + nat + morphism partials for the 64 gathered cells.
// Grid 32 x 512: threads [0,256) = src cell of morphism m, [256,512) = tgt.
// ---------------------------------------------------------------------------
__global__ __launch_bounds__(512) void k_tail(
    const float* __restrict__ hiddens,
    const float* __restrict__ W_ih, const float* __restrict__ W_hh,
    const float* __restrict__ b_ih, const float* __restrict__ b_hh,
    const float* __restrict__ nat_w, const float* __restrict__ morph_w,
    const int* __restrict__ msrc, const int* __restrict__ mtgt,
    const int* __restrict__ step, float* __restrict__ ws)
{
    __shared__ float mi[2][132];
    __shared__ float hh[2][256];
    __shared__ float hn[2][256];
    const int tid = threadIdx.x, half = tid >> 8, t = tid & 255, m = blockIdx.x;
    const int g = half * 32 + m;
    const int cell = half ? mtgt[m] : msrc[m];
    if (t < 129) mi[half][t] = ws[OFF_GBUF + g * 129 + t];
    hh[half][t] = hiddens[(size_t)cell * 256 + t];
    __syncthreads();

    float gi[3], gh[3];
#pragma unroll
    for (int p = 0; p < 3; ++p) {
        const int row = p * 256 + t;
        const float* wi = W_ih + row * 129;
        float s = b_ih[row];
        for (int j = 0; j < 129; ++j) s = fmaf(mi[half][j], wi[j], s);
        gi[p] = s;
        const float* wh = W_hh + (size_t)row * 256;
        float s2 = b_hh[row];
        for (int j = 0; j < 256; ++j) s2 = fmaf(hh[half][j], wh[j], s2);
        gh[p] = s2;
    }
    const float r  = 1.f / (1.f + expf(-(gi[0] + gh[0])));
    const float z  = 1.f / (1.f + expf(-(gi[1] + gh[1])));
    const float nn = tanhf(gi[2] + r * gh[2]);
    float hid = (1.f - z) * nn + z * hh[half][t];

    if (step[0] % 3 == 0) {
        hn[half][t] = hid;
        __syncthreads();
        float s = 0.f;
        const float* wr = nat_w + (size_t)t * 256;
        for (int j = 0; j < 256; ++j) s = fmaf(wr[j], hn[half][j], s);
        __syncthreads();
        hn[half][t] = s;
    } else {
        hn[half][t] = hid;
    }
    __syncthreads();

    const float* wm = morph_w + (size_t)m * 65536;
    float acc = 0.f;
    if (half == 0) {
        for (int j = 0; j < 256; ++j) acc = fmaf(wm[t * 256 + j], hn[0][j], acc);
        ws[OFF_PLIM + m * 256 + t] = acc;
    } else {
        for (int j = 0; j < 256; ++j) acc = fmaf(wm[j * 256 + t], hn[1][j], acc);
        ws[OFF_PCOL + m * 256 + t] = acc;
    }
}

// ---------------------------------------------------------------------------
// Out: blocks 0..127 -> combined_out[o]; block 128 -> avg_tension. 129 x 256.
// ---------------------------------------------------------------------------
__global__ __launch_bounds__(256) void k_out(const float* __restrict__ ws,
                                             float* __restrict__ out)
{
    __shared__ float red[256];
    const int b = blockIdx.x, t = threadIdx.x;
    if (b < 128) {
        float so = 0.f, se = 0.f;
        for (int i = t; i < 1024; i += 256) {
            so += ws[OFF_POUT + i * 128 + b];
            se += ws[OFF_PE + i];
        }
        red[t] = so; __syncthreads();
        for (int s = 128; s > 0; s >>= 1) { if (t < s) red[t] += red[t + s]; __syncthreads(); }
        const float SO = red[0]; __syncthreads();
        red[t] = se; __syncthreads();
        for (int s = 128; s > 0; s >>= 1) { if (t < s) red[t] += red[t + s]; __syncthreads(); }
        if (t == 0) out[b] = SO / red[0];
    } else {
        float pt = 0.f;
        for (int i = t; i < 1024; i += 256) pt += ws[OFF_PT + i];
        float L = 0.f, C = 0.f;
        for (int m = 0; m < 32; ++m) {
            L += ws[OFF_PLIM + m * 256 + t];
            C += ws[OFF_PCOL + m * 256 + t];
        }
        const float d = (L - C) * (1.f / 32.f);
        red[t] = d * d; __syncthreads();
        for (int s = 128; s > 0; s >>= 1) { if (t < s) red[t] += red[t + s]; __syncthreads(); }
        const float cat = red[0] * (1.f / 256.f); __syncthreads();
        red[t] = pt; __syncthreads();
        for (int s = 128; s > 0; s >>= 1) { if (t < s) red[t] += red[t + s]; __syncthreads(); }
        if (t == 0) out[128] = red[0] * (1.f / 65536.f) + 0.1f * cat;
    }
}

// ---------------------------------------------------------------------------
extern "C" void kernel_launch(void* const* d_in, const int* in_sizes, int n_in,
                              void* d_out, int out_size, void* d_ws, size_t ws_size,
                              hipStream_t stream)
{
    const float* x     = (const float*)d_in[0];
    const float* hidd  = (const float*)d_in[1];
    const float* Wa1   = (const float*)d_in[2];
    const float* ba1   = (const float*)d_in[3];
    const float* Wa2   = (const float*)d_in[4];
    const float* ba2   = (const float*)d_in[5];
    const float* Wg1   = (const float*)d_in[6];
    const float* bg1   = (const float*)d_in[7];
    const float* Wg2   = (const float*)d_in[8];
    const float* bg2   = (const float*)d_in[9];
    const float* W_ih  = (const float*)d_in[10];
    const float* W_hh  = (const float*)d_in[11];
    const float* b_ih  = (const float*)d_in[12];
    const float* b_hh  = (const float*)d_in[13];
    const float* nat_w = (const float*)d_in[14];
    const float* mw    = (const float*)d_in[15];
    const int*   msrc  = (const int*)d_in[16];
    const int*   mtgt  = (const int*)d_in[17];
    const int*   step  = (const int*)d_in[18];

    float* out = (float*)d_out;
    float* ws  = (float*)d_ws;

    k_prep<<<257, 256, 0, stream>>>(x, Wa1, ba1, Wa2, ba2, Wg1, bg1, Wg2, bg2, ws);
    k_main<<<1024, 512, 0, stream>>>(hidd, msrc, mtgt, ws);
    k_tail<<<32, 512, 0, stream>>>(hidd, W_ih, W_hh, b_ih, b_hh, nat_w, mw, msrc, mtgt, step, ws);
    k_out <<<129, 256, 0, stream>>>(ws, out);
}

// Round 3
// 83.006 us; speedup vs baseline: 3.7635x; 2.4121x over previous
//
#include <hip/hip_runtime.h>
#include <math.h>

#define N_CELLS 65536

// ---- workspace layout (float offsets), total ~1.29 MB ----
#define OFF_W1B   0          // bf16 [8s][4kc][256n][8j] = 65536 u16 = 32768 f
#define OFF_W2A   32768      // bf16 [8s][4kc][128o][8j] = 32768 u16 = 16384 f
#define OFF_XW1B  49152      // f32 [256]
#define OFF_B2D   49408      // f32 [128]
#define OFF_PT    49536      // f32 [1024]
#define OFF_PE    50560      // f32 [1024]
#define OFF_POUT  51584      // f32 [1024][128]
#define OFF_MI4   182656     // f32 [32 j4][64 g][4]  mem_in quads (transposed)
#define OFF_TEN   190848     // f32 [64]              tension per gathered cell
#define OFF_HH4   190912     // f32 [64 j4][64 g][4]  hiddens quads for gathered cells
#define OFF_GI    207296     // f32 [768][64]
#define OFF_GH    256448     // f32 [768][64]
#define OFF_PLIM  305600     // f32 [32][256]
#define OFF_PCOL  313792     // f32 [32][256]

typedef short bf16x8 __attribute__((ext_vector_type(8)));
typedef float f32x4  __attribute__((ext_vector_type(4)));

__device__ __forceinline__ unsigned short f2bf(float f) {
    unsigned u = __builtin_bit_cast(unsigned, f);
    u += 0x7FFFu + ((u >> 16) & 1u);          // round-to-nearest-even
    return (unsigned short)(u >> 16);
}

// ---------------------------------------------------------------------------
// Prep: pack W1/W2' to bf16 fragment layout, fold x@W1^T+b1, b2d, and build
// the transposed hiddens quads for the 64 gathered cells.  Grid 258 x 256.
// ---------------------------------------------------------------------------
__global__ __launch_bounds__(256) void k_prep(
    const float* __restrict__ x, const float* __restrict__ hiddens,
    const float* __restrict__ Wa1, const float* __restrict__ ba1,
    const float* __restrict__ Wa2, const float* __restrict__ ba2,
    const float* __restrict__ Wg1, const float* __restrict__ bg1,
    const float* __restrict__ Wg2, const float* __restrict__ bg2,
    const int* __restrict__ msrc, const int* __restrict__ mtgt,
    float* __restrict__ ws)
{
    const int b = blockIdx.x, t = threadIdx.x;
    unsigned short* w1b = (unsigned short*)(ws + OFF_W1B);
    unsigned short* w2a = (unsigned short*)(ws + OFF_W2A);
    if (b < 256) {
        const int n = b;           // t = k index (bits: s=t>>5, kc=(t>>3)&3, j=t&7)
        const float* row = (n < 128) ? &Wa1[n * 384] : &Wg1[(n - 128) * 384];
        const int sk = ((t >> 5) * 4 + ((t >> 3) & 3));
        w1b[(sk * 256 + n) * 8 + (t & 7)] = f2bf(row[128 + t]);
        if (n < 128) {   // W2'[o=n][k=t] : k<128 -> Wa2, else -Wg2
            float w2 = (t < 128) ? Wa2[n * 128 + t] : -Wg2[n * 128 + (t - 128)];
            w2a[(sk * 128 + n) * 8 + (t & 7)] = f2bf(w2);
        }
    } else if (b == 256) {
        const int n = t;
        const float* wr = (n < 128) ? &Wa1[n * 384] : &Wg1[(n - 128) * 384];
        float s = (n < 128) ? ba1[n] : bg1[n - 128];
        for (int j = 0; j < 128; ++j) s = fmaf(x[j], wr[j], s);
        ws[OFF_XW1B + n] = s;
        if (n < 128) ws[OFF_B2D + n] = ba2[n] - bg2[n];
    } else {
        // hiddens quads for gathered cells: HH4[(t>>2)][g][t&3] = hiddens[cell_g][t]
        for (int g = 0; g < 64; ++g) {
            const int cell = (g < 32) ? msrc[g] : mtgt[g - 32];
            ws[OFF_HH4 + (t >> 2) * 256 + g * 4 + (t & 3)] = hiddens[(size_t)cell * 256 + t];
        }
    }
}

// ---------------------------------------------------------------------------
// Main: 64-cell tile, both GEMMs via mfma_f32_16x16x32_bf16 (swapped operands:
// D[n][cell]).  Grid 1024 x 512.  LDS = 80KB -> 2 blocks/CU.
// ---------------------------------------------------------------------------
__global__ __launch_bounds__(512, 4) void k_main(
    const float* __restrict__ hiddens,
    const int* __restrict__ msrc, const int* __restrict__ mtgt,
    float* __restrict__ ws)
{
    __shared__ __align__(16) char smem[81920];
    short* hA  = (short*)&smem[0];
    short* h1A = (short*)&smem[32768];
    short* wbf = (short*)&smem[65536];

    const int tid  = threadIdx.x;
    const int lane = tid & 63;
    const int wid  = tid >> 6;
    const int wn   = wid >> 1;          // 0..3 : n-group (64n) / o-group (32o)
    const int wc   = wid & 1;           // 0..1 : cell-group (32 cells)
    const int l15  = lane & 15;
    const int l4   = lane >> 4;         // 0..3
    const int blk  = blockIdx.x;
    const int cell0 = blk * 64;

    // ---- stage hiddens tile f32 -> bf16, fragment layout [kc][slot][8] ----
    for (int it = 0; it < 4; ++it) {
        const int idx = it * 512 + tid;       // 0..2047
        const int c = idx >> 5, q = idx & 31; // cell, kc
        const float4* src = (const float4*)(hiddens + (size_t)(cell0 + c) * 256 + q * 8);
        float4 va = src[0], vb = src[1];
        bf16x8 bv;
        bv[0] = (short)f2bf(va.x); bv[1] = (short)f2bf(va.y);
        bv[2] = (short)f2bf(va.z); bv[3] = (short)f2bf(va.w);
        bv[4] = (short)f2bf(vb.x); bv[5] = (short)f2bf(vb.y);
        bv[6] = (short)f2bf(vb.z); bv[7] = (short)f2bf(vb.w);
        const int slot = (c & 48) | ((c ^ q) & 15);
        *(bf16x8*)&hA[(q * 64 + slot) * 8] = bv;
    }

    // ---- GEMM1: D1[n][c] = sum_k W1[n][k] * h[c][k] ----
    const uint4* w1g = (const uint4*)(ws + OFF_W1B);
    const uint4* w2g = (const uint4*)(ws + OFF_W2A);
    f32x4 acc[4][2];
#pragma unroll
    for (int nt = 0; nt < 4; ++nt)
#pragma unroll
        for (int ct = 0; ct < 2; ++ct) acc[nt][ct] = (f32x4)0.f;

    uint4 wr0 = w1g[tid], wr1 = w1g[512 + tid];
    for (int s = 0; s < 8; ++s) {
        __syncthreads();
        ((uint4*)wbf)[tid] = wr0; ((uint4*)wbf)[512 + tid] = wr1;
        __syncthreads();
        if (s < 7) { wr0 = w1g[(s + 1) * 1024 + tid]; wr1 = w1g[(s + 1) * 1024 + 512 + tid]; }
        else       { wr0 = w2g[tid]; }   // prefetch GEMM2 chunk 0
        const int kcg = s * 4 + l4;
        bf16x8 afr[4], bfr[2];
#pragma unroll
        for (int nt = 0; nt < 4; ++nt)
            afr[nt] = *(const bf16x8*)&wbf[(l4 * 256 + wn * 64 + nt * 16 + l15) * 8];
#pragma unroll
        for (int ct = 0; ct < 2; ++ct) {
            const int slot = (wc * 32 + ct * 16) | ((l15 ^ kcg) & 15);
            bfr[ct] = *(const bf16x8*)&hA[(kcg * 64 + slot) * 8];
        }
#pragma unroll
        for (int nt = 0; nt < 4; ++nt)
#pragma unroll
            for (int ct = 0; ct < 2; ++ct)
                acc[nt][ct] = __builtin_amdgcn_mfma_f32_16x16x32_bf16(afr[nt], bfr[ct], acc[nt][ct], 0, 0, 0);
    }

    // ---- bias + relu + write h1 (bf16, fragment layout, k2 = n) ----
#pragma unroll
    for (int nt = 0; nt < 4; ++nt) {
#pragma unroll
        for (int r = 0; r < 4; ++r) {
            const int n = wn * 64 + nt * 16 + l4 * 4 + r;
            const float xb = ws[OFF_XW1B + n];
            const int kc2 = n >> 3, j2 = n & 7;
#pragma unroll
            for (int ct = 0; ct < 2; ++ct) {
                const int c = wc * 32 + ct * 16 + l15;
                float v = fmaxf(acc[nt][ct][r] + xb, 0.f);
                const int slot = (c & 48) | ((c ^ kc2) & 15);
                h1A[(kc2 * 64 + slot) * 8 + j2] = (short)f2bf(v);
            }
        }
    }

    // ---- GEMM2: D2[o][c] = sum_n W2'[o][n] * h1[c][n] ----
    f32x4 acc2[2][2];
#pragma unroll
    for (int ot = 0; ot < 2; ++ot)
#pragma unroll
        for (int ct = 0; ct < 2; ++ct) acc2[ot][ct] = (f32x4)0.f;

    for (int s = 0; s < 8; ++s) {
        __syncthreads();
        ((uint4*)wbf)[tid] = wr0;
        __syncthreads();
        if (s < 7) wr0 = w2g[(s + 1) * 512 + tid];
        const int kcg = s * 4 + l4;
        bf16x8 afr2[2], bfr2[2];
#pragma unroll
        for (int ot = 0; ot < 2; ++ot)
            afr2[ot] = *(const bf16x8*)&wbf[(l4 * 128 + wn * 32 + ot * 16 + l15) * 8];
#pragma unroll
        for (int ct = 0; ct < 2; ++ct) {
            const int slot = (wc * 32 + ct * 16) | ((l15 ^ kcg) & 15);
            bfr2[ct] = *(const bf16x8*)&h1A[(kcg * 64 + slot) * 8];
        }
#pragma unroll
        for (int ot = 0; ot < 2; ++ot)
#pragma unroll
            for (int ct = 0; ct < 2; ++ct)
                acc2[ot][ct] = __builtin_amdgcn_mfma_f32_16x16x32_bf16(afr2[ot], bfr2[ct], acc2[ot][ct], 0, 0, 0);
    }

    // ---- epilogue ----
    float outv[2][2][4];
#pragma unroll
    for (int ot = 0; ot < 2; ++ot)
#pragma unroll
        for (int r = 0; r < 4; ++r) {
            const int o = wn * 32 + ot * 16 + l4 * 4 + r;
            const float bd = ws[OFF_B2D + o];
#pragma unroll
            for (int ct = 0; ct < 2; ++ct)
                outv[ot][ct][r] = acc2[ot][ct][r] + bd;
        }
    __syncthreads();   // all LDS frag reads done; re-purpose smem

    float* out_sm = (float*)smem;                 // [64][130]
    float* part   = (float*)&smem[65536];         // [4][64]
    float* e_sm   = (float*)&smem[65536 + 1024];  // [64]
    float* t_sm   = (float*)&smem[65536 + 1280];  // [64]

#pragma unroll
    for (int ot = 0; ot < 2; ++ot)
#pragma unroll
        for (int ct = 0; ct < 2; ++ct) {
            const int c = wc * 32 + ct * 16 + l15;
#pragma unroll
            for (int r = 0; r < 4; ++r) {
                const int o = wn * 32 + ot * 16 + l4 * 4 + r;
                out_sm[c * 130 + o] = outv[ot][ct][r];
            }
        }
#pragma unroll
    for (int ct = 0; ct < 2; ++ct) {
        float sq = 0.f;
#pragma unroll
        for (int ot = 0; ot < 2; ++ot)
#pragma unroll
            for (int r = 0; r < 4; ++r) sq = fmaf(outv[ot][ct][r], outv[ot][ct][r], sq);
        sq += __shfl_xor(sq, 16);
        sq += __shfl_xor(sq, 32);
        if (l4 == 0) part[wn * 64 + wc * 32 + ct * 16 + l15] = sq;
    }
    __syncthreads();

    if (tid < 64) {
        const float tv = (part[tid] + part[64 + tid] + part[128 + tid] + part[192 + tid]) * (1.f / 128.f);
        const float ev = expf(tv);
        t_sm[tid] = tv; e_sm[tid] = ev;
        float pt = tv, pe = ev;
        for (int off = 32; off > 0; off >>= 1) {
            pt += __shfl_down(pt, off);
            pe += __shfl_down(pe, off);
        }
        if (tid == 0) { ws[OFF_PT + blk] = pt; ws[OFF_PE + blk] = pe; }
    }
    __syncthreads();

    if (tid < 128) {
        float s = 0.f;
        for (int c = 0; c < 64; ++c) s = fmaf(e_sm[c], out_sm[c * 130 + tid], s);
        ws[OFF_POUT + blk * 128 + tid] = s;
    } else if (tid < 192) {
        const int g = tid - 128;
        const int cell = (g < 32) ? msrc[g] : mtgt[g - 32];
        if ((cell >> 6) == blk) {
            const int c = cell & 63;
            for (int o = 0; o < 128; ++o)
                ws[OFF_MI4 + (o >> 2) * 256 + g * 4 + (o & 3)] = out_sm[c * 130 + o];
            ws[OFF_TEN + g] = t_sm[c];
        }
    }
}

// ---------------------------------------------------------------------------
// Tail1: gi/gh for all 768 gate-rows x 64 gathered cells.  Grid 192 x 256.
// Wave = one row (weights broadcast via SGPR), lane = cell (coalesced quads).
// ---------------------------------------------------------------------------
__global__ __launch_bounds__(256) void k_tail1(
    const float* __restrict__ W_ih, const float* __restrict__ W_hh,
    const float* __restrict__ b_ih, const float* __restrict__ b_hh,
    float* __restrict__ ws)
{
    const int lane = threadIdx.x & 63;
    const int w    = threadIdx.x >> 6;
    const int row  = __builtin_amdgcn_readfirstlane(blockIdx.x * 4 + w);
    const float* mi4 = ws + OFF_MI4;
    const float* hh4 = ws + OFF_HH4;

    const float* wi = W_ih + row * 129;
    float gi = b_ih[row];
#pragma unroll 8
    for (int q = 0; q < 32; ++q) {
        float4 a = *(const float4*)(mi4 + q * 256 + lane * 4);
        gi = fmaf(wi[4 * q + 0], a.x, gi);
        gi = fmaf(wi[4 * q + 1], a.y, gi);
        gi = fmaf(wi[4 * q + 2], a.z, gi);
        gi = fmaf(wi[4 * q + 3], a.w, gi);
    }
    gi = fmaf(ws[OFF_TEN + lane], wi[128], gi);

    const float* wh = W_hh + (size_t)row * 256;
    float gh = b_hh[row];
#pragma unroll 8
    for (int q = 0; q < 64; ++q) {
        float4 a = *(const float4*)(hh4 + q * 256 + lane * 4);
        float4 b = *(const float4*)(wh + 4 * q);
        gh = fmaf(b.x, a.x, gh);
        gh = fmaf(b.y, a.y, gh);
        gh = fmaf(b.z, a.z, gh);
        gh = fmaf(b.w, a.w, gh);
    }
    ws[OFF_GI + row * 64 + lane] = gi;
    ws[OFF_GH + row * 64 + lane] = gh;
}

// ---------------------------------------------------------------------------
// Tail2: GRU elementwise + nat + morphism partials.  Grid 32 x 512.
// threads [0,256) = src cell of morphism m (limit), [256,512) = tgt (colimit).
// ---------------------------------------------------------------------------
__global__ __launch_bounds__(512) void k_tail2(
    const float* __restrict__ nat_w, const float* __restrict__ morph_w,
    const int* __restrict__ step, float* __restrict__ ws)
{
    __shared__ float hd[2][256];
    __shared__ float hn[2][256];
    const int tid = threadIdx.x, half = tid >> 8, t = tid & 255, m = blockIdx.x;
    const int g = half * 32 + m;

    const float i_r = ws[OFF_GI + (0 * 256 + t) * 64 + g];
    const float i_z = ws[OFF_GI + (1 * 256 + t) * 64 + g];
    const float i_n = ws[OFF_GI + (2 * 256 + t) * 64 + g];
    const float h_r = ws[OFF_GH + (0 * 256 + t) * 64 + g];
    const float h_z = ws[OFF_GH + (1 * 256 + t) * 64 + g];
    const float h_n = ws[OFF_GH + (2 * 256 + t) * 64 + g];
    const float hv  = ws[OFF_HH4 + (t >> 2) * 256 + g * 4 + (t & 3)];

    const float r  = 1.f / (1.f + expf(-(i_r + h_r)));
    const float z  = 1.f / (1.f + expf(-(i_z + h_z)));
    const float nn = tanhf(i_n + r * h_n);
    const float hid = (1.f - z) * nn + z * hv;

    hd[half][t] = hid;
    __syncthreads();
    if (step[0] % 3 == 0) {
        const float4* wr = (const float4*)(nat_w + (size_t)t * 256);
        float s = 0.f;
        for (int q = 0; q < 64; ++q) {
            float4 wq = wr[q];
            s = fmaf(wq.x, hd[half][4 * q + 0], s);
            s = fmaf(wq.y, hd[half][4 * q + 1], s);
            s = fmaf(wq.z, hd[half][4 * q + 2], s);
            s = fmaf(wq.w, hd[half][4 * q + 3], s);
        }
        hn[half][t] = s;
    } else {
        hn[half][t] = hid;
    }
    __syncthreads();

    const float* wm = morph_w + (size_t)m * 65536;
    if (half == 0) {
        const float4* r_ = (const float4*)(wm + (size_t)t * 256);
        float L = 0.f;
        for (int q = 0; q < 64; ++q) {
            float4 wq = r_[q];
            L = fmaf(wq.x, hn[0][4 * q + 0], L);
            L = fmaf(wq.y, hn[0][4 * q + 1], L);
            L = fmaf(wq.z, hn[0][4 * q + 2], L);
            L = fmaf(wq.w, hn[0][4 * q + 3], L);
        }
        ws[OFF_PLIM + m * 256 + t] = L;
    } else {
        float C = 0.f;
        for (int j = 0; j < 256; ++j)
            C = fmaf(wm[j * 256 + t], hn[1][j], C);
        ws[OFF_PCOL + m * 256 + t] = C;
    }
}

// ---------------------------------------------------------------------------
// Out: blocks 0..127 -> combined_out[o]; block 128 -> avg_tension. 129 x 256.
// ---------------------------------------------------------------------------
__global__ __launch_bounds__(256) void k_out(const float* __restrict__ ws,
                                             float* __restrict__ out)
{
    __shared__ float red[256];
    const int b = blockIdx.x, t = threadIdx.x;
    if (b < 128) {
        float so = 0.f, se = 0.f;
        for (int i = t; i < 1024; i += 256) {
            so += ws[OFF_POUT + i * 128 + b];
            se += ws[OFF_PE + i];
        }
        red[t] = so; __syncthreads();
        for (int s = 128; s > 0; s >>= 1) { if (t < s) red[t] += red[t + s]; __syncthreads(); }
        const float SO = red[0]; __syncthreads();
        red[t] = se; __syncthreads();
        for (int s = 128; s > 0; s >>= 1) { if (t < s) red[t] += red[t + s]; __syncthreads(); }
        if (t == 0) out[b] = SO / red[0];
    } else {
        float pt = 0.f;
        for (int i = t; i < 1024; i += 256) pt += ws[OFF_PT + i];
        float L = 0.f, C = 0.f;
        for (int m = 0; m < 32; ++m) {
            L += ws[OFF_PLIM + m * 256 + t];
            C += ws[OFF_PCOL + m * 256 + t];
        }
        const float d = (L - C) * (1.f / 32.f);
        red[t] = d * d; __syncthreads();
        for (int s = 128; s > 0; s >>= 1) { if (t < s) red[t] += red[t + s]; __syncthreads(); }
        const float cat = red[0] * (1.f / 256.f); __syncthreads();
        red[t] = pt; __syncthreads();
        for (int s = 128; s > 0; s >>= 1) { if (t < s) red[t] += red[t + s]; __syncthreads(); }
        if (t == 0) out[128] = red[0] * (1.f / 65536.f) + 0.1f * cat;
    }
}

// ---------------------------------------------------------------------------
extern "C" void kernel_launch(void* const* d_in, const int* in_sizes, int n_in,
                              void* d_out, int out_size, void* d_ws, size_t ws_size,
                              hipStream_t stream)
{
    const float* x     = (const float*)d_in[0];
    const float* hidd  = (const float*)d_in[1];
    const float* Wa1   = (const float*)d_in[2];
    const float* ba1   = (const float*)d_in[3];
    const float* Wa2   = (const float*)d_in[4];
    const float* ba2   = (const float*)d_in[5];
    const float* Wg1   = (const float*)d_in[6];
    const float* bg1   = (const float*)d_in[7];
    const float* Wg2   = (const float*)d_in[8];
    const float* bg2   = (const float*)d_in[9];
    const float* W_ih  = (const float*)d_in[10];
    const float* W_hh  = (const float*)d_in[11];
    const float* b_ih  = (const float*)d_in[12];
    const float* b_hh  = (const float*)d_in[13];
    const float* nat_w = (const float*)d_in[14];
    const float* mw    = (const float*)d_in[15];
    const int*   msrc  = (const int*)d_in[16];
    const int*   mtgt  = (const int*)d_in[17];
    const int*   step  = (const int*)d_in[18];

    float* out = (float*)d_out;
    float* ws  = (float*)d_ws;

    k_prep <<<258, 256, 0, stream>>>(x, hidd, Wa1, ba1, Wa2, ba2, Wg1, bg1, Wg2, bg2, msrc, mtgt, ws);
    k_main <<<1024, 512, 0, stream>>>(hidd, msrc, mtgt, ws);
    k_tail1<<<192, 256, 0, stream>>>(W_ih, W_hh, b_ih, b_hh, ws);
    k_tail2<<<32, 512, 0, stream>>>(nat_w, mw, step, ws);
    k_out  <<<129, 256, 0, stream>>>(ws, out);
}